// Round 1
// baseline (233.240 us; speedup 1.0000x reference)
//
#include <hip/hip_runtime.h>

#define NROW 8192
#define NF   128

typedef float f32x4  __attribute__((ext_vector_type(4)));
typedef int   i32x4  __attribute__((ext_vector_type(4)));
typedef short bf16x8 __attribute__((ext_vector_type(8)));
typedef short bf16x4 __attribute__((ext_vector_type(4)));

__device__ __forceinline__ short f2bf(float f) {
    union { float f; unsigned u; } v; v.f = f;
    unsigned r = v.u + 0x7FFFu + ((v.u >> 16) & 1u);
    return (short)(r >> 16);
}

// k0: WT[c][k] = bf16(W[k][c])   (128x128, tiny)
__global__ __launch_bounds__(256) void k0_wt(const float* __restrict__ W,
                                             short* __restrict__ WT) {
    int idx = blockIdx.x * 256 + threadIdx.x;
    int c = idx >> 7, k = idx & 127;
    WT[c * NF + k] = f2bf(W[k * NF + c]);
}

// k1: Wh = mo @ W via bf16 MFMA; writes WhT (bf16, transposed 128x8192),
//     s1 = Wh@a1, s2 = Wh@a2 (f32).
__global__ __launch_bounds__(256) void k1_wh(const float* __restrict__ mo,
        const short* __restrict__ WT,
        const float* __restrict__ a1, const float* __restrict__ a2,
        short* __restrict__ WhT, float* __restrict__ s1g, float* __restrict__ s2g) {
    __shared__ float s_lds[2][32];
    int t = threadIdx.x;
    int w = t >> 6, l = t & 63, lg = l >> 4, lr = l & 15;
    int rows0 = blockIdx.x * 32;
    if (t < 64) s_lds[t >> 5][t & 31] = 0.0f;
    __syncthreads();

    f32x4 acc[2][2] = {}; // [rt][ct]
#pragma unroll
    for (int ks = 0; ks < 4; ++ks) {
        bf16x8 a[2], b[2];
#pragma unroll
        for (int rt = 0; rt < 2; ++rt) {
            const float* ap = mo + (size_t)(rows0 + rt*16 + lr) * NF + ks*32 + lg*8;
            f32x4 x0 = *(const f32x4*)ap;
            f32x4 x1 = *(const f32x4*)(ap + 4);
#pragma unroll
            for (int e = 0; e < 4; ++e) { a[rt][e] = f2bf(x0[e]); a[rt][4+e] = f2bf(x1[e]); }
        }
#pragma unroll
        for (int ct = 0; ct < 2; ++ct) {
            int c = w*32 + ct*16 + lr;
            b[ct] = *(const bf16x8*)(WT + c*NF + ks*32 + lg*8);
        }
#pragma unroll
        for (int rt = 0; rt < 2; ++rt)
#pragma unroll
            for (int ct = 0; ct < 2; ++ct)
                acc[rt][ct] = __builtin_amdgcn_mfma_f32_16x16x32_bf16(a[rt], b[ct], acc[rt][ct], 0, 0, 0);
    }

    // epilogue: C/D layout (verified): col = lane&15, row = (lane>>4)*4 + reg
#pragma unroll
    for (int rt = 0; rt < 2; ++rt) {
        float p1[4] = {0,0,0,0}, p2[4] = {0,0,0,0};
#pragma unroll
        for (int ct = 0; ct < 2; ++ct) {
            int c = w*32 + ct*16 + lr;
            float a1c = a1[c], a2c = a2[c];
            bf16x4 wv;
#pragma unroll
            for (int g = 0; g < 4; ++g) {
                float v = acc[rt][ct][g];
                wv[g] = f2bf(v);
                p1[g] += v * a1c;
                p2[g] += v * a2c;
            }
            int r0 = rows0 + rt*16 + lg*4;
            *(bf16x4*)(WhT + (size_t)c * NROW + r0) = wv;
        }
#pragma unroll
        for (int off = 1; off < 16; off <<= 1) {
#pragma unroll
            for (int g = 0; g < 4; ++g) {
                p1[g] += __shfl_xor(p1[g], off);
                p2[g] += __shfl_xor(p2[g], off);
            }
        }
        if (lr == 0) {
            int rloc = rt*16 + lg*4;
#pragma unroll
            for (int g = 0; g < 4; ++g) {
                atomicAdd(&s_lds[0][rloc+g], p1[g]);
                atomicAdd(&s_lds[1][rloc+g], p2[g]);
            }
        }
    }
    __syncthreads();
    if (t < 32)       s1g[rows0 + t]        = s_lds[0][t];
    else if (t < 64)  s2g[rows0 + (t - 32)] = s_lds[1][t - 32];
}

// k2: fused mask + exp(leakyrelu) + PV accumulate. One wave owns 16 rows and a
// j-segment; P computed straight into MFMA A fragments (no LDS, no barriers).
__global__ __launch_bounds__(256, 2) void k2_main(
        const int* __restrict__ adj, const short* __restrict__ WhT,
        const float* __restrict__ s1g, const float* __restrict__ s2g,
        float* __restrict__ numP, float* __restrict__ zP,
        int S, int npb) {
    int t = threadIdx.x;
    int w = t >> 6, l = t & 63, lg = l >> 4, lr = l & 15;
    int b = blockIdx.x;
    int jseg = b % S, rowblk = b / S;
    int rows0 = rowblk * 64 + w * 16;
    int row = rows0 + lr;
    float s1v = s1g[row];
    const size_t arow = (size_t)row * NROW;
    int jbase = jseg * npb;
    int NT = npb >> 6;

    f32x4 acc[8] = {};
    float z = 0.0f;

    const short* bptr[8];
#pragma unroll
    for (int ct = 0; ct < 8; ++ct)
        bptr[ct] = WhT + (size_t)(ct*16 + lr) * NROW + jbase + lg*8;

#define LD_TILE(A0,A1,A2,A3,S0,S1,S2,S3,JT) do { \
    const int* ap_ = adj + arow + (JT) + lg*8; \
    A0 = __builtin_nontemporal_load((const i32x4*)ap_); \
    A1 = __builtin_nontemporal_load((const i32x4*)(ap_ + 4)); \
    A2 = __builtin_nontemporal_load((const i32x4*)(ap_ + 32)); \
    A3 = __builtin_nontemporal_load((const i32x4*)(ap_ + 36)); \
    const float* sp_ = s2g + (JT) + lg*8; \
    S0 = *(const f32x4*)sp_;        S1 = *(const f32x4*)(sp_ + 4); \
    S2 = *(const f32x4*)(sp_ + 32); S3 = *(const f32x4*)(sp_ + 36); \
} while (0)

#define DO4(AV, SV, FR, O) do { \
_Pragma("unroll") \
    for (int e = 0; e < 4; ++e) { \
        float x_ = s1v + SV[e]; \
        float lk_ = fmaxf(x_, 0.2f * x_); \
        float pe_ = __expf(lk_); \
        pe_ = (AV[e] > 0) ? pe_ : 0.0f; \
        z += pe_; \
        FR[(O) + e] = f2bf(pe_); \
    } \
} while (0)

#define PROC(A0,A1,A2,A3,S0,S1,S2,S3) do { \
    bf16x8 fa0, fa1; \
    DO4(A0, S0, fa0, 0); DO4(A1, S1, fa0, 4); \
    DO4(A2, S2, fa1, 0); DO4(A3, S3, fa1, 4); \
_Pragma("unroll") \
    for (int ct = 0; ct < 8; ++ct) { \
        bf16x8 b0 = *(const bf16x8*)bptr[ct]; \
        bf16x8 b1 = *(const bf16x8*)(bptr[ct] + 32); \
        acc[ct] = __builtin_amdgcn_mfma_f32_16x16x32_bf16(fa0, b0, acc[ct], 0, 0, 0); \
        acc[ct] = __builtin_amdgcn_mfma_f32_16x16x32_bf16(fa1, b1, acc[ct], 0, 0, 0); \
        bptr[ct] += 64; \
    } \
} while (0)

    i32x4 a0, a1_, a2_, a3; f32x4 c0, c1, c2, c3;
    i32x4 d0, d1, d2, d3;   f32x4 e0, e1, e2, e3;
    LD_TILE(a0,a1_,a2_,a3, c0,c1,c2,c3, jbase);
    for (int it = 0; it < NT; it += 2) {
        int j1 = jbase + (it + 1) * 64;
        LD_TILE(d0,d1,d2,d3, e0,e1,e2,e3, j1);
        PROC(a0,a1_,a2_,a3, c0,c1,c2,c3);
        int j2 = (it + 2 < NT) ? (jbase + (it + 2) * 64) : jbase;
        LD_TILE(a0,a1_,a2_,a3, c0,c1,c2,c3, j2);
        PROC(d0,d1,d2,d3, e0,e1,e2,e3);
    }

    z += __shfl_xor(z, 16);
    z += __shfl_xor(z, 32);
    if (l < 16) zP[(size_t)jseg * NROW + row] = z;

    size_t obase = (size_t)jseg * NROW * NF;
#pragma unroll
    for (int ct = 0; ct < 8; ++ct) {
        int c = ct * 16 + lr;
        int r0 = rows0 + lg * 4;
#pragma unroll
        for (int g = 0; g < 4; ++g)
            numP[obase + (size_t)(r0 + g) * NF + c] = acc[ct][g];
    }
#undef LD_TILE
#undef DO4
#undef PROC
}

// k3: out = elu( sum_s num / sum_s z )
__global__ __launch_bounds__(256) void k3_reduce(const float* __restrict__ numP,
        const float* __restrict__ zP, float* __restrict__ out, int S) {
    int idx = blockIdx.x * 256 + threadIdx.x;
    int r = idx >> 7;
    float num = 0.0f, zz = 0.0f;
    for (int s = 0; s < S; ++s) {
        num += numP[(size_t)s * (NROW * NF) + idx];
        zz  += zP[s * NROW + r];
    }
    float h = num / zz;
    out[idx] = (h > 0.0f) ? h : expm1f(h);
}

extern "C" void kernel_launch(void* const* d_in, const int* in_sizes, int n_in,
                              void* d_out, int out_size, void* d_ws, size_t ws_size,
                              hipStream_t stream) {
    const float* mo  = (const float*)d_in[0];
    const int*   adj = (const int*)d_in[1];
    const float* W   = (const float*)d_in[2];
    const float* a1  = (const float*)d_in[3];
    const float* a2  = (const float*)d_in[4];
    float* out = (float*)d_out;

    char* p = (char*)d_ws;
    short* WT  = (short*)p;  p += (size_t)NF * NF * 2;
    short* WhT = (short*)p;  p += (size_t)NF * NROW * 2;
    float* s1  = (float*)p;  p += (size_t)NROW * 4;
    float* s2  = (float*)p;  p += (size_t)NROW * 4;
    float* zP  = (float*)p;  p += (size_t)4 * NROW * 4;   // reserved for S<=4
    size_t fixed = (size_t)(p - (char*)d_ws);

    int S = 4;
    while (S > 1 && fixed + (size_t)S * NROW * NF * 4 > ws_size) S >>= 1;
    float* numP = (float*)p;
    if (fixed + (size_t)S * NROW * NF * 4 > ws_size) numP = out;  // S==1 in-place fallback

    k0_wt<<<dim3(64), dim3(256), 0, stream>>>(W, WT);
    k1_wh<<<dim3(256), dim3(256), 0, stream>>>(mo, WT, a1, a2, WhT, s1, s2);
    k2_main<<<dim3(128 * S), dim3(256), 0, stream>>>(adj, WhT, s1, s2, numP, zP, S, NROW / S);
    k3_reduce<<<dim3(NROW * NF / 256), dim3(256), 0, stream>>>(numP, zP, out, S);
}

// Round 2
// 171.336 us; speedup vs baseline: 1.3613x; 1.3613x over previous
//
#include <hip/hip_runtime.h>

#define NROW 8192
#define NF   128

typedef float f32x4  __attribute__((ext_vector_type(4)));
typedef int   i32x4  __attribute__((ext_vector_type(4)));
typedef short bf16x8 __attribute__((ext_vector_type(8)));
typedef short bf16x4 __attribute__((ext_vector_type(4)));

__device__ __forceinline__ short f2bf(float f) {
    union { float f; unsigned u; } v; v.f = f;
    unsigned r = v.u + 0x7FFFu + ((v.u >> 16) & 1u);
    return (short)(r >> 16);
}

// k0: WT[c][k] = bf16(W[k][c])   (128x128, tiny)
__global__ __launch_bounds__(256) void k0_wt(const float* __restrict__ W,
                                             short* __restrict__ WT) {
    int idx = blockIdx.x * 256 + threadIdx.x;
    int c = idx >> 7, k = idx & 127;
    WT[c * NF + k] = f2bf(W[k * NF + c]);
}

// k1: Wh = mo @ W via bf16 MFMA; writes WhT (bf16, transposed 128x8192),
//     s1 = Wh@a1, s2 = Wh@a2 (f32).
__global__ __launch_bounds__(256) void k1_wh(const float* __restrict__ mo,
        const short* __restrict__ WT,
        const float* __restrict__ a1, const float* __restrict__ a2,
        short* __restrict__ WhT, float* __restrict__ s1g, float* __restrict__ s2g) {
    __shared__ float s_lds[2][32];
    int t = threadIdx.x;
    int w = t >> 6, l = t & 63, lg = l >> 4, lr = l & 15;
    int rows0 = blockIdx.x * 32;
    if (t < 64) s_lds[t >> 5][t & 31] = 0.0f;
    __syncthreads();

    f32x4 acc[2][2] = {}; // [rt][ct]
#pragma unroll
    for (int ks = 0; ks < 4; ++ks) {
        bf16x8 a[2], b[2];
#pragma unroll
        for (int rt = 0; rt < 2; ++rt) {
            const float* ap = mo + (size_t)(rows0 + rt*16 + lr) * NF + ks*32 + lg*8;
            f32x4 x0 = *(const f32x4*)ap;
            f32x4 x1 = *(const f32x4*)(ap + 4);
#pragma unroll
            for (int e = 0; e < 4; ++e) { a[rt][e] = f2bf(x0[e]); a[rt][4+e] = f2bf(x1[e]); }
        }
#pragma unroll
        for (int ct = 0; ct < 2; ++ct) {
            int c = w*32 + ct*16 + lr;
            b[ct] = *(const bf16x8*)(WT + c*NF + ks*32 + lg*8);
        }
#pragma unroll
        for (int rt = 0; rt < 2; ++rt)
#pragma unroll
            for (int ct = 0; ct < 2; ++ct)
                acc[rt][ct] = __builtin_amdgcn_mfma_f32_16x16x32_bf16(a[rt], b[ct], acc[rt][ct], 0, 0, 0);
    }

    // epilogue: C/D layout: col = lane&15, row = (lane>>4)*4 + reg
#pragma unroll
    for (int rt = 0; rt < 2; ++rt) {
        float p1[4] = {0,0,0,0}, p2[4] = {0,0,0,0};
#pragma unroll
        for (int ct = 0; ct < 2; ++ct) {
            int c = w*32 + ct*16 + lr;
            float a1c = a1[c], a2c = a2[c];
            bf16x4 wv;
#pragma unroll
            for (int g = 0; g < 4; ++g) {
                float v = acc[rt][ct][g];
                wv[g] = f2bf(v);
                p1[g] += v * a1c;
                p2[g] += v * a2c;
            }
            int r0 = rows0 + rt*16 + lg*4;
            *(bf16x4*)(WhT + (size_t)c * NROW + r0) = wv;
        }
#pragma unroll
        for (int off = 1; off < 16; off <<= 1) {
#pragma unroll
            for (int g = 0; g < 4; ++g) {
                p1[g] += __shfl_xor(p1[g], off);
                p2[g] += __shfl_xor(p2[g], off);
            }
        }
        if (lr == 0) {
            int rloc = rt*16 + lg*4;
#pragma unroll
            for (int g = 0; g < 4; ++g) {
                atomicAdd(&s_lds[0][rloc+g], p1[g]);
                atomicAdd(&s_lds[1][rloc+g], p2[g]);
            }
        }
    }
    __syncthreads();
    if (t < 32)       s1g[rows0 + t]        = s_lds[0][t];
    else if (t < 64)  s2g[rows0 + (t - 32)] = s_lds[1][t - 32];
}

// k2: block = 4 waves on the SAME 16 rows, in-block j-split x4, cross-block x S.
// Per wave, per 64-j tile: coalesced NT stage of adj (lane=(row,16j-chunk)),
// exp/mask computed in stage layout, bf16 P through private LDS tile (no
// barriers in main loop), MFMA A-frags read back, B-frags streamed from L2.
__global__ __launch_bounds__(256, 4) void k2_main(
        const int* __restrict__ adj, const short* __restrict__ WhT,
        const float* __restrict__ s1g, const float* __restrict__ s2g,
        float* __restrict__ numP, float* __restrict__ zP,
        int S, int npb) {
    __shared__ __attribute__((aligned(16))) short Pl[4][2][16][72];
    __shared__ __attribute__((aligned(16))) float Lacc[2][2048];
    __shared__ float Lz[16];

    int t = threadIdx.x, w = t >> 6, l = t & 63;
    int lr = l & 15, lg = l >> 4;     // fragment-side lane decomposition
    int rr = l >> 2, q = l & 3;       // stage-side: row rr, 16-j chunk q
    int b = blockIdx.x, jseg = b % S, rg = b / S;
    int rows0 = rg << 4;

    if (t < 16) Lz[t] = 0.0f;
    __syncthreads();

    int nwt = npb >> 2;               // j span per wave
    int jb  = jseg * npb + w * nwt;
    int NT  = nwt >> 6;

    float s1v = s1g[rows0 + rr];
    const int* arow = adj + (size_t)(rows0 + rr) * NROW;

    f32x4 acc[8] = {};
    float z = 0.0f;

    i32x4 A[4]; f32x4 Sv[4];
#pragma unroll
    for (int c = 0; c < 4; ++c) {
        A[c]  = __builtin_nontemporal_load((const i32x4*)(arow + jb + c*16 + q*4));
        Sv[c] = *(const f32x4*)(s2g + jb + c*16 + q*4);
    }

    int d = 0;
    for (int it = 0; it < NT; ++it) {
        int jt = jb + (it << 6);
        // --- exp/mask in stage layout, write bf16 P tile to LDS ---
        short* Pw = &Pl[w][d][rr][0];
#pragma unroll
        for (int c = 0; c < 4; ++c) {
            bf16x4 pv;
#pragma unroll
            for (int e = 0; e < 4; ++e) {
                float x  = s1v + Sv[c][e];
                float lk = fmaxf(x, 0.2f * x);
                float p  = __expf(lk);
                p = (A[c][e] > 0) ? p : 0.0f;
                z += p;
                pv[e] = f2bf(p);
            }
            *(bf16x4*)(Pw + c*16 + q*4) = pv;
        }
        // --- prefetch next tile (hides HBM latency under MFMA phase) ---
        if (it + 1 < NT) {
            int jn = jt + 64;
#pragma unroll
            for (int c = 0; c < 4; ++c) {
                A[c]  = __builtin_nontemporal_load((const i32x4*)(arow + jn + c*16 + q*4));
                Sv[c] = *(const f32x4*)(s2g + jn + c*16 + q*4);
            }
        }
        // --- A-frags from LDS (same-wave RAW, compiler waits lgkmcnt) ---
        const short* Pr = &Pl[w][d][lr][0];
        bf16x8 fa0 = *(const bf16x8*)(Pr + lg*8);
        bf16x8 fa1 = *(const bf16x8*)(Pr + 32 + lg*8);
#pragma unroll
        for (int ct = 0; ct < 8; ++ct) {
            const short* bp = WhT + (size_t)(ct*16 + lr) * NROW + jt + lg*8;
            bf16x8 b0 = *(const bf16x8*)bp;
            bf16x8 b1 = *(const bf16x8*)(bp + 32);
            acc[ct] = __builtin_amdgcn_mfma_f32_16x16x32_bf16(fa0, b0, acc[ct], 0, 0, 0);
            acc[ct] = __builtin_amdgcn_mfma_f32_16x16x32_bf16(fa1, b1, acc[ct], 0, 0, 0);
        }
        d ^= 1;
    }

    // --- z: reduce the 4 chunk-lanes of each row, accumulate across waves ---
    z += __shfl_xor(z, 1);
    z += __shfl_xor(z, 2);
    if (q == 0) atomicAdd(&Lz[rr], z);
    __syncthreads();
    if (t < 16) zP[(size_t)jseg * NROW + rows0 + t] = Lz[t];

    // --- acc: tree-reduce 4 waves (identical (lane,ct,g)->(row,col) maps) ---
    if (w >= 2) {
        float* s0 = &Lacc[w - 2][0];
#pragma unroll
        for (int ct = 0; ct < 8; ++ct) *(f32x4*)(s0 + ct*256 + l*4) = acc[ct];
    }
    __syncthreads();
    if (w < 2) {
        const float* s0 = &Lacc[w][0];
#pragma unroll
        for (int ct = 0; ct < 8; ++ct) acc[ct] += *(const f32x4*)(s0 + ct*256 + l*4);
    }
    __syncthreads();
    if (w == 1) {
        float* s0 = &Lacc[0][0];
#pragma unroll
        for (int ct = 0; ct < 8; ++ct) *(f32x4*)(s0 + ct*256 + l*4) = acc[ct];
    }
    __syncthreads();
    if (w == 0) {
        const float* s0 = &Lacc[0][0];
        size_t obase = (size_t)jseg * NROW * NF;
#pragma unroll
        for (int ct = 0; ct < 8; ++ct) {
            acc[ct] += *(const f32x4*)(s0 + ct*256 + l*4);
            int cc = ct*16 + lr;
            int r0 = rows0 + lg*4;
#pragma unroll
            for (int g = 0; g < 4; ++g)
                numP[obase + (size_t)(r0 + g) * NF + cc] = acc[ct][g];
        }
    }
}

// k3: out = elu( sum_s num / sum_s z )
__global__ __launch_bounds__(256) void k3_reduce(const float* __restrict__ numP,
        const float* __restrict__ zP, float* __restrict__ out, int S) {
    int idx = blockIdx.x * 256 + threadIdx.x;
    int r = idx >> 7;
    float num = 0.0f, zz = 0.0f;
    for (int s = 0; s < S; ++s) {
        num += numP[(size_t)s * (NROW * NF) + idx];
        zz  += zP[s * NROW + r];
    }
    float h = num / zz;
    out[idx] = (h > 0.0f) ? h : expm1f(h);
}

extern "C" void kernel_launch(void* const* d_in, const int* in_sizes, int n_in,
                              void* d_out, int out_size, void* d_ws, size_t ws_size,
                              hipStream_t stream) {
    const float* mo  = (const float*)d_in[0];
    const int*   adj = (const int*)d_in[1];
    const float* W   = (const float*)d_in[2];
    const float* a1  = (const float*)d_in[3];
    const float* a2  = (const float*)d_in[4];
    float* out = (float*)d_out;

    char* p = (char*)d_ws;
    short* WT  = (short*)p;  p += (size_t)NF * NF * 2;
    short* WhT = (short*)p;  p += (size_t)NF * NROW * 2;
    float* s1  = (float*)p;  p += (size_t)NROW * 4;
    float* s2  = (float*)p;  p += (size_t)NROW * 4;
    float* zP  = (float*)p;  p += (size_t)4 * NROW * 4;   // reserved for S<=4
    size_t fixed = (size_t)(p - (char*)d_ws);

    int S = 4;
    while (S > 1 && fixed + (size_t)S * NROW * NF * 4 > ws_size) S >>= 1;
    float* numP = (float*)p;
    if (fixed + (size_t)S * NROW * NF * 4 > ws_size) numP = out;  // S==1 in-place fallback

    k0_wt<<<dim3(64), dim3(256), 0, stream>>>(W, WT);
    k1_wh<<<dim3(256), dim3(256), 0, stream>>>(mo, WT, a1, a2, WhT, s1, s2);
    k2_main<<<dim3((NROW / 16) * S), dim3(256), 0, stream>>>(adj, WhT, s1, s2, numP, zP, S, NROW / S);
    k3_reduce<<<dim3(NROW * NF / 256), dim3(256), 0, stream>>>(numP, zP, out, S);
}